// Round 14
// baseline (269.921 us; speedup 1.0000x reference)
//
#include <hip/hip_runtime.h>
#include <stdint.h>

#define BATCH 4
#define NPTS 4096
#define KNN 11            // K+1 neighbors including self
#define LPQ 16            // lanes per query
#define QPB 16            // queries per block
#define NC 16             // grid cells per axis (cell = 0.625)
#define NCELL (NC*NC*NC)  // 4096
#define GMIN (-5.0f)
#define INV_CSZ 1.6f      // 1/0.625
#define SENT_BITS 0x433FFFFFFFFFFFFFll

// ws layout (bytes): sorted float4 | orig idx | cell_start
#define WS_SRT 0          // 4*4096*16 = 262144
#define WS_OID 262144     // 4*4096*4  =  65536
#define WS_CST 327680     // 4*4097*4  =  65552

// monotone float <-> uint (ascending order preserved)
__device__ __forceinline__ unsigned sortable_f32(float d) {
    unsigned b = __float_as_uint(d);
    unsigned m = (unsigned)(((int)b) >> 31) | 0x80000000u;
    return b ^ m;
}
__device__ __forceinline__ float unsortable_f32(unsigned u) {
    unsigned b = (u & 0x80000000u) ? (u ^ 0x80000000u) : ~u;
    return __uint_as_float(b);
}
__device__ __forceinline__ int cell_of(float v) {
    int c = (int)floorf((v - GMIN) * INV_CSZ);
    return c < 0 ? 0 : (c > NC-1 ? NC-1 : c);
}

// ---------------- build: counting-sort by cell (NC=16) ----------------
// One block (512 thr) per batch. hist in LDS (16 KB); scan = per-thread
// sequential over 8 cells + Hillis-Steele over 512 thread-totals.
__global__ __launch_bounds__(512) void build_kernel(
    const float* __restrict__ pos, float4* __restrict__ srt,
    unsigned* __restrict__ oid, unsigned* __restrict__ cst)
{
#pragma clang fp contract(off)
    __shared__ unsigned hist[NCELL];
    __shared__ unsigned scanT[512];
    int b = blockIdx.x, tid = threadIdx.x;
    const float* pb = pos + (size_t)b * NPTS * 3;

    for (int k = tid; k < NCELL; k += 512) hist[k] = 0;
    __syncthreads();

    float px[8], py[8], pz[8]; int pc[8];
#pragma unroll
    for (int u = 0; u < 8; ++u) {
        int j = tid + u * 512;
        float x = pb[3*j], y = pb[3*j+1], z = pb[3*j+2];
        px[u] = x; py[u] = y; pz[u] = z;
        int cid = (cell_of(z)*NC + cell_of(y))*NC + cell_of(x);
        pc[u] = cid;
        atomicAdd(&hist[cid], 1u);
    }
    __syncthreads();

    unsigned loc[8], sum = 0;
#pragma unroll
    for (int k = 0; k < 8; ++k) { loc[k] = sum; sum += hist[tid*8 + k]; }
    scanT[tid] = sum;
    __syncthreads();
    for (int off = 1; off < 512; off <<= 1) {
        unsigned add = (tid >= off) ? scanT[tid - off] : 0u;
        __syncthreads();
        scanT[tid] += add;
        __syncthreads();
    }
    unsigned base = tid ? scanT[tid-1] : 0u;

    unsigned* cb = cst + (size_t)b * (NCELL + 1);
#pragma unroll
    for (int k = 0; k < 8; ++k) cb[tid*8 + k] = base + loc[k];
    if (tid == 0) cb[NCELL] = NPTS;
    __syncthreads();
#pragma unroll
    for (int k = 0; k < 8; ++k) hist[tid*8 + k] = base + loc[k];  // cursors
    __syncthreads();

#pragma unroll
    for (int u = 0; u < 8; ++u) {
        int j = tid + u * 512;
        unsigned dst = atomicAdd(&hist[pc[u]], 1u);
        float x = px[u], y = py[u], z = pz[u];
        float sq = x*x + y*y + z*z;       // FROZEN: elementwise sq, seq sum
        srt[(size_t)b*NPTS + dst] = make_float4(x, y, z, sq);
        oid[(size_t)b*NPTS + dst] = (unsigned)j;
    }
}

// ------- search: exact 11-NN over span rows (balanced) + fused MLP ------
// FROZEN d2 (verified r4-r13); f64 packed keys (d2 asc, orig-j asc).
// tau = 11th frozen-d2 of a 16-pt sorted-order window (upper-bounds the true
// 11th); span = cells covering the rad-ball with r9's proven slack. Span rows
// (ez,ey,cx0..cx1) are CONTIGUOUS sorted ranges; lanes stride the global
// candidate rank mod 16 -> balanced + coalesced. M >= 11 guaranteed (window
// points lie in the ball). No gate/flush: M is small, inserts are cheap.
__global__ __launch_bounds__(256, 4) void search_kernel(
    const float4* __restrict__ srt, const unsigned* __restrict__ oid,
    const unsigned* __restrict__ cst,
    const float* __restrict__ pos, const float* __restrict__ vel,
    const float* __restrict__ initc,
    const float* __restrict__ W1, const float* __restrict__ b1,
    const float* __restrict__ W2, const float* __restrict__ b2,
    const float* __restrict__ W3, const float* __restrict__ b3,
    float* __restrict__ out)
{
#pragma clang fp contract(off)
    __shared__ unsigned sC[NCELL + 1];

    int b    = blockIdx.x >> 8;           // 256 blocks per batch
    int qblk = blockIdx.x & 255;
    int tid  = threadIdx.x;
    for (int k = tid; k < NCELL + 1; k += 256)
        sC[k] = cst[(size_t)b*(NCELL+1) + k];
    __syncthreads();

    int q = tid >> 4, p = tid & 15;
    int s = qblk * QPB + q;               // this query's SORTED slot
    const float4* sp4 = srt + (size_t)b * NPTS;
    const unsigned* od = oid + (size_t)b * NPTS;

    float4 qp = sp4[s];
    float xq = qp.x, yq = qp.y, zq = qp.z, sqq = qp.w;

    // ---- tau: 16-lane bitonic sort of the window d2's (10 shfl steps) ----
    int wlo = s - 8; wlo = wlo < 0 ? 0 : (wlo > NPTS-16 ? NPTS-16 : wlo);
    float4 wc = sp4[wlo + p];
    float tw = xq*wc.x; tw = fmaf(yq, wc.y, tw); tw = fmaf(zq, wc.z, tw);
    float wd2 = (sqq + wc.w) - 2.0f*tw;   // FROZEN d2
    unsigned v = sortable_f32(wd2);
#pragma unroll
    for (int k = 2; k <= 16; k <<= 1) {
#pragma unroll
        for (int j = k >> 1; j > 0; j >>= 1) {
            unsigned o = (unsigned)__shfl_xor((int)v, j, LPQ);
            bool takeMin = (((p & j) == 0) == ((p & k) == 0));
            unsigned mn = v < o ? v : o;
            unsigned mx = v < o ? o : v;
            v = takeMin ? mn : mx;
        }
    }
    unsigned tau_u = (unsigned)__shfl((int)v, 10, LPQ);  // 11th smallest
    float tauf = unsortable_f32(tau_u);
    float tcmp = tauf * 1.0002f + 2e-3f;  // slack >> fp32 rounding (r9-proven)
    float rad  = sqrtf(fmaxf(tcmp, 0.0f)) + 1e-4f;

    int cx0 = cell_of(xq - rad), cx1 = cell_of(xq + rad);
    int cy0 = cell_of(yq - rad), cy1 = cell_of(yq + rad);
    int cz0 = cell_of(zq - rad), cz1 = cell_of(zq + rad);
    int nxc = cx1 - cx0 + 1;

    double kd[KNN];
#pragma unroll
    for (int k = 0; k < KNN; ++k) kd[k] = __longlong_as_double(SENT_BITS);

    unsigned cum = 0;
    for (int ez = cz0; ez <= cz1; ++ez) {
        for (int ey = cy0; ey <= cy1; ++ey) {
            int cid0 = (ez*NC + ey)*NC + cx0;
            unsigned rs  = sC[cid0];
            unsigned len = sC[cid0 + nxc] - rs;
            // smallest global rank >= cum with rank % 16 == p
            unsigned first = cum + (((unsigned)p - cum) & 15u);
            for (unsigned g = first; g < cum + len; g += 16) {
                unsigned tt = rs + (g - cum);
                float4 cc = sp4[tt];
                float t = xq*cc.x;        // FROZEN d2 arithmetic
                t = fmaf(yq, cc.y, t);
                t = fmaf(zq, cc.z, t);
                float d2 = (sqq + cc.w) - 2.0f*t;
                unsigned u = sortable_f32(d2);
                unsigned lo = (u << 12) | od[tt];
                unsigned hi = 0x43300000u | (u >> 20);
                double key = __longlong_as_double(
                    ((long long)(int)hi << 32) | (unsigned long long)lo);
#pragma unroll
                for (int k = KNN-1; k > 0; --k) {
                    double mn = fmin(kd[k], key);
                    kd[k] = fmax(kd[k-1], mn);
                }
                kd[0] = fmin(kd[0], key);
            }
            cum += len;
        }
    }

    // destructive 16-lane merge (r8 verbatim) -> res[] = original indices
    unsigned res[KNN];
#pragma unroll
    for (int r = 0; r < KNN; ++r) {
        double h = kd[0];
#pragma unroll
        for (int m = 1; m <= 8; m <<= 1)
            h = fmin(h, __shfl_xor(h, m, LPQ));
        long long hb = __double_as_longlong(h);
        res[r] = (unsigned)(hb & 0xFFF);
        bool own = (__double_as_longlong(kd[0]) == hb);
#pragma unroll
        for (int t = 0; t < KNN-1; ++t) kd[t] = own ? kd[t+1] : kd[t];
        kd[KNN-1] = own ? __longlong_as_double(SENT_BITS) : kd[KNN-1];
    }

    // ---------- fused MLP, lane-parallel, BIT-IDENTICAL to r8/r9 ----------
    const float* pbo = pos + (size_t)b * NPTS * 3;   // ORIGINAL arrays
    const float* vb  = vel + (size_t)b * NPTS * 3;

    const float* w0 = W1 + (2*p)   * 66;
    const float* w1 = W1 + (2*p+1) * 66;
    float a0 = b1[2*p], a1 = b1[2*p+1];
#pragma unroll
    for (int k = 1; k < KNN; ++k) {       // ff 0..29: relative positions
        const float* pn = pbo + 3*(int)res[k];
        float dx = pn[0] - xq, dy = pn[1] - yq, dz = pn[2] - zq;
        int ff = 3*(k-1);
        a0 = fmaf(dx, w0[ff+0], a0); a1 = fmaf(dx, w1[ff+0], a1);
        a0 = fmaf(dy, w0[ff+1], a0); a1 = fmaf(dy, w1[ff+1], a1);
        a0 = fmaf(dz, w0[ff+2], a0); a1 = fmaf(dz, w1[ff+2], a1);
    }
#pragma unroll
    for (int k = 0; k < KNN; ++k) {       // ff 30..62: velocities
        const float* vn = vb + 3*(int)res[k];
        int ff = 30 + 3*k;
        a0 = fmaf(vn[0], w0[ff+0], a0); a1 = fmaf(vn[0], w1[ff+0], a1);
        a0 = fmaf(vn[1], w0[ff+1], a0); a1 = fmaf(vn[1], w1[ff+1], a1);
        a0 = fmaf(vn[2], w0[ff+2], a0); a1 = fmaf(vn[2], w1[ff+2], a1);
    }
    float c0i = initc[b*3+0], c1i = initc[b*3+1], c2i = initc[b*3+2];
    a0 = fmaf(c0i, w0[63], a0); a1 = fmaf(c0i, w1[63], a1);
    a0 = fmaf(c1i, w0[64], a0); a1 = fmaf(c1i, w1[64], a1);
    a0 = fmaf(c2i, w0[65], a0); a1 = fmaf(c2i, w1[65], a1);

    float h2 = b2[p];
    const float* w2 = W2 + p * 32;
#pragma unroll
    for (int ii = 0; ii < 32; ++ii) {
        float h1v = __shfl((ii & 1) ? a1 : a0, ii >> 1, LPQ);
        h2 = fmaf(h1v, w2[ii], h2);
    }
    int o3 = p < 6 ? p : 0;
    float po = b3[o3];
    const float* w3 = W3 + o3 * 16;
#pragma unroll
    for (int ii = 0; ii < 16; ++ii) {
        float h2v = __shfl(h2, ii, LPQ);
        po = fmaf(h2v, w3[ii], po);
    }
    float resid = (p == 0) ? xq : (p == 1) ? yq : (p == 2) ? zq : 0.0f;
    po += resid;                           // residual on first 3 channels

    unsigned oq = od[s];                   // original row of this query
    if (p < 6)
        out[((size_t)b * NPTS + (size_t)oq) * 6 + p] = po;
}

extern "C" void kernel_launch(void* const* d_in, const int* in_sizes, int n_in,
                              void* d_out, int out_size, void* d_ws, size_t ws_size,
                              hipStream_t stream) {
    const float* pos   = (const float*)d_in[0];
    const float* vel   = (const float*)d_in[1];
    const float* initc = (const float*)d_in[2];
    const float* W1    = (const float*)d_in[3];
    const float* b1    = (const float*)d_in[4];
    const float* W2    = (const float*)d_in[5];
    const float* b2    = (const float*)d_in[6];
    const float* W3    = (const float*)d_in[7];
    const float* b3    = (const float*)d_in[8];
    float* out = (float*)d_out;

    float4*   srt  = (float4*)((char*)d_ws + WS_SRT);
    unsigned* oidp = (unsigned*)((char*)d_ws + WS_OID);
    unsigned* cstp = (unsigned*)((char*)d_ws + WS_CST);

    build_kernel<<<dim3(BATCH), dim3(512), 0, stream>>>(pos, srt, oidp, cstp);
    search_kernel<<<dim3(BATCH * 256), dim3(256), 0, stream>>>(
        srt, oidp, cstp, pos, vel, initc, W1, b1, W2, b2, W3, b3, out);
}

// Round 15
// 212.563 us; speedup vs baseline: 1.2698x; 1.2698x over previous
//
#include <hip/hip_runtime.h>
#include <stdint.h>

#define BATCH 4
#define NPTS 4096
#define KNN 11            // K+1 neighbors including self
#define LPQ 32            // lanes per query -> 8192 waves (8/SIMD grid-side)
#define QPB 8             // queries per block (256 threads / 32 lanes)
#define CPL (NPTS / LPQ)  // 128 candidates per lane
#define BUFN 8            // per-lane qualifier buffer slots (16 KB LDS)
#define SENT_BITS 0x433FFFFFFFFFFFFFll

// monotone float -> uint mapping (ascending)
__device__ __forceinline__ unsigned sortable_f32(float d) {
    unsigned b = __float_as_uint(d);
    unsigned m = (unsigned)(((int)b) >> 31) | 0x80000000u;
    return b ^ m;
}

// prep: float4(x,y,z,sq) in natural order, FROZEN bits (verified r4-r13):
//   sq = fl(fl(x*x)+fl(y*y)) + fl(z*z)  (elementwise square, seq sum, no fma)
__global__ __launch_bounds__(256) void prep_kernel(
    const float* __restrict__ pos, float4* __restrict__ srt)
{
#pragma clang fp contract(off)
    int t = blockIdx.x * 256 + threadIdx.x;   // 0..16383
    float x = pos[3*t], y = pos[3*t+1], z = pos[3*t+2];
    float sq = x*x + y*y + z*z;
    srt[t] = make_float4(x, y, z, sq);
}

// Fused exact 11-NN + MLP. FROZEN d2 (r4-r13): dot = fma chain from fl(x*x');
// d2 = fl(sqq+sqj) - fl(2*dot). top-k asc d2, ties -> lower index; key =
// double with bits 0x433<<52 | sortable(d2)<<12 | j (f64 order == lex order).
// r15: NO LDS staging, NO barriers — candidates read straight from the
// L2-resident prep array (per-lane sequential streams); LDS holds only the
// r11-style append buffer. LPQ=32 doubles waves/SIMD (latency hiding).
__global__ __launch_bounds__(256, 6) void fused_kernel(
    const float4* __restrict__ srt,
    const float* __restrict__ pos, const float* __restrict__ vel,
    const float* __restrict__ initc,
    const float* __restrict__ W1, const float* __restrict__ b1,
    const float* __restrict__ W2, const float* __restrict__ b2,
    const float* __restrict__ W3, const float* __restrict__ b3,
    float* __restrict__ out)
{
#pragma clang fp contract(off)
    // slot-major lane-private buffers: lanes 8B apart -> 2-way -> free
    __shared__ unsigned long long buf[BUFN * 256];

    int b    = blockIdx.x >> 9;           // 512 blocks per batch
    int qblk = blockIdx.x & 511;
    int tid  = threadIdx.x;

    int q = tid >> 5, p = tid & 31;
    int i = qblk * QPB + q;               // query index within batch

    const float4* cb = srt + (size_t)b * NPTS;
    float4 qp = cb[i];                    // frozen bits from prep
    float xq = qp.x, yq = qp.y, zq = qp.z, sqq = qp.w;

    double kd[KNN];
#pragma unroll
    for (int k = 0; k < KNN; ++k) kd[k] = __longlong_as_double(SENT_BITS);
    float tau_f = __builtin_inff();       // stale-conservative gate threshold
    int cnt = 0, nflush = 0;

    int jg = p * CPL;                     // this lane's candidate range
    for (int jl = 0; jl < CPL; jl += 4) {
        // 4 back-to-back global loads (sequential per lane, L1/L2-hot)
        float4 c0 = cb[jg + jl + 0];
        float4 c1 = cb[jg + jl + 1];
        float4 c2 = cb[jg + jl + 2];
        float4 c3 = cb[jg + jl + 3];
        float t0 = xq*c0.x, t1 = xq*c1.x, t2 = xq*c2.x, t3 = xq*c3.x;
        t0 = fmaf(yq, c0.y, t0); t1 = fmaf(yq, c1.y, t1);
        t2 = fmaf(yq, c2.y, t2); t3 = fmaf(yq, c3.y, t3);
        t0 = fmaf(zq, c0.z, t0); t1 = fmaf(zq, c1.z, t1);
        t2 = fmaf(zq, c2.z, t2); t3 = fmaf(zq, c3.z, t3);
        float d0 = (sqq + c0.w) - 2.0f*t0;
        float d1 = (sqq + c1.w) - 2.0f*t1;
        float d2 = (sqq + c2.w) - 2.0f*t2;
        float d3 = (sqq + c3.w) - 2.0f*t3;

        // f32 gate (== u32 gate by monotonicity); pack only on accept
#pragma unroll
        for (int s = 0; s < 4; ++s) {
            float dv = s == 0 ? d0 : s == 1 ? d1 : s == 2 ? d2 : d3;
            if (dv <= tau_f) {
                unsigned u  = sortable_f32(dv);
                unsigned lo = (u << 12) | (unsigned)(jg + jl + s);
                unsigned hi = 0x43300000u | (u >> 20);
                buf[cnt * 256 + tid] =
                    ((unsigned long long)hi << 32) | (unsigned long long)lo;
                ++cnt;
            }
        }

        if (__any(cnt > BUFN - 4)) {      // +<=4 per group -> never exceeds 8
            // ---- flush: drain buffers through the f64 network ----
            for (int k = 0; k < BUFN; ++k) {
                if (!__any(cnt > k)) break;
                unsigned long long kb = buf[k * 256 + tid];
                double key = (k < cnt) ? __longlong_as_double(kb)
                                       : __longlong_as_double(SENT_BITS);
#pragma unroll
                for (int kk = KNN-1; kk > 0; --kk) {
                    double mn = fmin(kd[kk], key);
                    kd[kk] = fmax(kd[kk-1], mn);
                }
                kd[0] = fmin(kd[0], key);
            }
            cnt = 0;
            if (nflush < 3) {             // exact tau only while it matters
                ++nflush;
                double tmp[KNN];
#pragma unroll
                for (int k = 0; k < KNN; ++k) tmp[k] = kd[k];
                double h = tmp[0];
#pragma unroll
                for (int r = 0; r < KNN; ++r) {
                    h = tmp[0];
#pragma unroll
                    for (int m = 1; m <= 16; m <<= 1)
                        h = fmin(h, __shfl_xor(h, m, LPQ));
                    bool own = (__double_as_longlong(tmp[0]) ==
                                __double_as_longlong(h));
#pragma unroll
                    for (int t2 = 0; t2 < KNN-1; ++t2)
                        tmp[t2] = own ? tmp[t2+1] : tmp[t2];
                    tmp[KNN-1] = own ? __longlong_as_double(SENT_BITS)
                                     : tmp[KNN-1];
                }
                unsigned tau_u = (unsigned)((unsigned long long)
                                            __double_as_longlong(h) >> 12);
                tau_f = __uint_as_float(tau_u ^ 0x80000000u);
            }
        }
    }

    // final drain
    for (int k = 0; k < BUFN; ++k) {
        if (!__any(cnt > k)) break;
        unsigned long long kb = buf[k * 256 + tid];
        double key = (k < cnt) ? __longlong_as_double(kb)
                               : __longlong_as_double(SENT_BITS);
#pragma unroll
        for (int kk = KNN-1; kk > 0; --kk) {
            double mn = fmin(kd[kk], key);
            kd[kk] = fmax(kd[kk-1], mn);
        }
        kd[0] = fmin(kd[0], key);
    }

    // destructive 32-lane merge (r12-verified) -> res[] = original indices
    unsigned res[KNN];
#pragma unroll
    for (int r = 0; r < KNN; ++r) {
        double h = kd[0];
#pragma unroll
        for (int m = 1; m <= 16; m <<= 1)
            h = fmin(h, __shfl_xor(h, m, LPQ));
        long long hb = __double_as_longlong(h);
        res[r] = (unsigned)(hb & 0xFFF);
        bool own = (__double_as_longlong(kd[0]) == hb);
#pragma unroll
        for (int t = 0; t < KNN-1; ++t) kd[t] = own ? kd[t+1] : kd[t];
        kd[KNN-1] = own ? __longlong_as_double(SENT_BITS) : kd[KNN-1];
    }

    // ---------- fused MLP, lane-parallel (r12-verified, bit-identical) ------
    const float* pb = pos + (size_t)b * NPTS * 3;
    const float* vb = vel + (size_t)b * NPTS * 3;
    int pm = p & 15;

    const float* w0 = W1 + (2*pm)   * 66;
    const float* w1 = W1 + (2*pm+1) * 66;
    float a0 = b1[2*pm], a1 = b1[2*pm+1];
#pragma unroll
    for (int k = 1; k < KNN; ++k) {       // ff 0..29: relative positions
        const float* pn = pb + 3*(int)res[k];
        float dx = pn[0] - xq, dy = pn[1] - yq, dz = pn[2] - zq;
        int ff = 3*(k-1);
        a0 = fmaf(dx, w0[ff+0], a0); a1 = fmaf(dx, w1[ff+0], a1);
        a0 = fmaf(dy, w0[ff+1], a0); a1 = fmaf(dy, w1[ff+1], a1);
        a0 = fmaf(dz, w0[ff+2], a0); a1 = fmaf(dz, w1[ff+2], a1);
    }
#pragma unroll
    for (int k = 0; k < KNN; ++k) {       // ff 30..62: velocities
        const float* vn = vb + 3*(int)res[k];
        int ff = 30 + 3*k;
        a0 = fmaf(vn[0], w0[ff+0], a0); a1 = fmaf(vn[0], w1[ff+0], a1);
        a0 = fmaf(vn[1], w0[ff+1], a0); a1 = fmaf(vn[1], w1[ff+1], a1);
        a0 = fmaf(vn[2], w0[ff+2], a0); a1 = fmaf(vn[2], w1[ff+2], a1);
    }
    float c0i = initc[b*3+0], c1i = initc[b*3+1], c2i = initc[b*3+2];
    a0 = fmaf(c0i, w0[63], a0); a1 = fmaf(c0i, w1[63], a1);
    a0 = fmaf(c1i, w0[64], a0); a1 = fmaf(c1i, w1[64], a1);
    a0 = fmaf(c2i, w0[65], a0); a1 = fmaf(c2i, w1[65], a1);

    float h2 = b2[pm];
    const float* w2 = W2 + pm * 32;
#pragma unroll
    for (int ii = 0; ii < 32; ++ii) {
        float h1v = __shfl((ii & 1) ? a1 : a0, ii >> 1, LPQ);
        h2 = fmaf(h1v, w2[ii], h2);
    }
    int o3 = pm < 6 ? pm : 0;
    float po = b3[o3];
    const float* w3 = W3 + o3 * 16;
#pragma unroll
    for (int ii = 0; ii < 16; ++ii) {
        float h2v = __shfl(h2, ii, LPQ);  // rows 0..15 live on lanes 0..15
        po = fmaf(h2v, w3[ii], po);
    }
    float resid = (p == 0) ? xq : (p == 1) ? yq : (p == 2) ? zq : 0.0f;
    po += resid;                           // residual on first 3 channels

    if (p < 6)
        out[((size_t)b * NPTS + (size_t)i) * 6 + p] = po;
}

extern "C" void kernel_launch(void* const* d_in, const int* in_sizes, int n_in,
                              void* d_out, int out_size, void* d_ws, size_t ws_size,
                              hipStream_t stream) {
    const float* pos   = (const float*)d_in[0];
    const float* vel   = (const float*)d_in[1];
    const float* initc = (const float*)d_in[2];
    const float* W1    = (const float*)d_in[3];
    const float* b1    = (const float*)d_in[4];
    const float* W2    = (const float*)d_in[5];
    const float* b2    = (const float*)d_in[6];
    const float* W3    = (const float*)d_in[7];
    const float* b3    = (const float*)d_in[8];
    float* out = (float*)d_out;
    float4* srt = (float4*)d_ws;          // 16384 * 16 B = 256 KB

    prep_kernel<<<dim3(BATCH * NPTS / 256), dim3(256), 0, stream>>>(pos, srt);
    fused_kernel<<<dim3(BATCH * (NPTS / QPB)), dim3(256), 0, stream>>>(
        srt, pos, vel, initc, W1, b1, W2, b2, W3, b3, out);
}

// Round 16
// 127.309 us; speedup vs baseline: 2.1202x; 1.6697x over previous
//
#include <hip/hip_runtime.h>
#include <stdint.h>

#define BATCH 4
#define NPTS 4096
#define KNN 11            // K+1 neighbors including self
#define LPQ 16            // lanes per query
#define QPB 16            // queries per block
#define CHUNK 1024        // LDS candidate chunk
#define NCHUNK (NPTS / CHUNK)     // 4
#define CPL (CHUNK / LPQ)         // 64 candidates per lane per chunk
#define BUFN 10           // per-lane qualifier buffer slots
#define SENT_BITS 0x433FFFFFFFFFFFFFll

// monotone float -> uint mapping (ascending)
__device__ __forceinline__ unsigned sortable_f32(float d) {
    unsigned b = __float_as_uint(d);
    unsigned m = (unsigned)(((int)b) >> 31) | 0x80000000u;
    return b ^ m;
}

// Fused exact 11-NN + MLP. FROZEN d2 arithmetic (verified r4-r15):
//   sq_j = fl(fl(x2)+fl(y2)) + fl(z2); dot = fma chain; d2 = fl(si+sj)-fl(2t).
// top-k ascending d2, ties -> lower index; key = double with bits
// 0x433<<52 | sortable(d2)<<12 | j  (f64 order == (d2 asc, j asc)).
// r16 = r11 base (tau merge EVERY flush — r13 showed freezing was negative)
// with a tighter flush trigger: cnt > BUFN-2 checked twice per 4-candidate
// group (<=2 appends between checks -> never exceeds BUFN). Buffers fill to
// ~9.5/10 instead of ~6.5/10 -> ~25% fewer flushes -> fewer 1.5K-cyc merges.
__global__ __launch_bounds__(256, 4) void fused_kernel(
    const float* __restrict__ pos, const float* __restrict__ vel,
    const float* __restrict__ initc,
    const float* __restrict__ W1, const float* __restrict__ b1,
    const float* __restrict__ W2, const float* __restrict__ b2,
    const float* __restrict__ W3, const float* __restrict__ b3,
    float* __restrict__ out)
{
#pragma clang fp contract(off)
    // skewed float4 (x,y,z,sq): idx + (idx>>6) -> partitions offset by 16B
    __shared__ float4 sp[CHUNK + LPQ];
    // slot-major lane-private buffers: lanes 8B apart -> 2-way -> free
    __shared__ unsigned long long buf[BUFN * 256];

    int b    = blockIdx.x >> 8;           // 256 blocks per batch
    int qblk = blockIdx.x & 255;
    int tid  = threadIdx.x;
    const float* pb = pos + (size_t)b * NPTS * 3;

    int q = tid >> 4, p = tid & 15;
    int i = qblk * QPB + q;               // query index within batch

    float xq = pb[3*i], yq = pb[3*i+1], zq = pb[3*i+2];
    float sqq = xq*xq + yq*yq + zq*zq;    // contract(off): np sum order

    double kd[KNN];
#pragma unroll
    for (int k = 0; k < KNN; ++k) kd[k] = __longlong_as_double(SENT_BITS);
    float tau_f = __builtin_inff();       // stale-conservative gate threshold
    int cnt = 0;

    // flush: drain buffers through the f64 insert network, then exact
    // running tau via non-destructive 16-lane pop-merge (r11-verbatim)
    auto flush = [&]() {
        for (int k = 0; k < BUFN; ++k) {
            if (!__any(cnt > k)) break;   // early out
            unsigned long long kb = buf[k * 256 + tid];
            double key = (k < cnt) ? __longlong_as_double(kb)
                                   : __longlong_as_double(SENT_BITS);
#pragma unroll
            for (int kk = KNN-1; kk > 0; --kk) {
                double mn = fmin(kd[kk], key);
                kd[kk] = fmax(kd[kk-1], mn);
            }
            kd[0] = fmin(kd[0], key);
        }
        cnt = 0;
        double tmp[KNN];
#pragma unroll
        for (int k = 0; k < KNN; ++k) tmp[k] = kd[k];
        double h = tmp[0];
#pragma unroll
        for (int r = 0; r < KNN; ++r) {
            h = tmp[0];
#pragma unroll
            for (int m = 1; m <= 8; m <<= 1)
                h = fmin(h, __shfl_xor(h, m, LPQ));
            bool own = (__double_as_longlong(tmp[0]) ==
                        __double_as_longlong(h));
#pragma unroll
            for (int t2 = 0; t2 < KNN-1; ++t2)
                tmp[t2] = own ? tmp[t2+1] : tmp[t2];
            tmp[KNN-1] = own ? __longlong_as_double(SENT_BITS) : tmp[KNN-1];
        }
        unsigned tau_u = (unsigned)((unsigned long long)
                                    __double_as_longlong(h) >> 12);
        tau_f = __uint_as_float(tau_u ^ 0x80000000u);  // real keys: top bit set
    };

    for (int c = 0; c < NCHUNK; ++c) {
        if (c) __syncthreads();
        for (int j = tid; j < CHUNK; j += 256) {
            int g = c * CHUNK + j;
            float x = pb[3*g], y = pb[3*g+1], z = pb[3*g+2];
            float sq = x*x + y*y + z*z;   // FROZEN staged sq
            sp[j + (j >> 6)] = make_float4(x, y, z, sq);
        }
        __syncthreads();

        int sbase = p * (CPL + 1);
        int jg    = c * CHUNK + p * CPL;
        for (int jl = 0; jl < CPL; jl += 4) {
            // 4 back-to-back LDS reads + 4 independent d2 chains (ILP)
            float4 c0 = sp[sbase + jl + 0];
            float4 c1 = sp[sbase + jl + 1];
            float4 c2 = sp[sbase + jl + 2];
            float4 c3 = sp[sbase + jl + 3];
            float t0 = xq*c0.x, t1 = xq*c1.x, t2 = xq*c2.x, t3 = xq*c3.x;
            t0 = fmaf(yq, c0.y, t0); t1 = fmaf(yq, c1.y, t1);
            t2 = fmaf(yq, c2.y, t2); t3 = fmaf(yq, c3.y, t3);
            t0 = fmaf(zq, c0.z, t0); t1 = fmaf(zq, c1.z, t1);
            t2 = fmaf(zq, c2.z, t2); t3 = fmaf(zq, c3.z, t3);
            float d0 = (sqq + c0.w) - 2.0f*t0;
            float d1 = (sqq + c1.w) - 2.0f*t1;
            float d2 = (sqq + c2.w) - 2.0f*t2;
            float d3 = (sqq + c3.w) - 2.0f*t3;

            // f32 gate (== u32 gate by monotonicity); pack only on accept
#pragma unroll
            for (int s = 0; s < 2; ++s) {
                float dv = s == 0 ? d0 : d1;
                if (dv <= tau_f) {
                    unsigned u  = sortable_f32(dv);
                    unsigned lo = (u << 12) | (unsigned)(jg + jl + s);
                    unsigned hi = 0x43300000u | (u >> 20);
                    buf[cnt * 256 + tid] =
                        ((unsigned long long)hi << 32) | (unsigned long long)lo;
                    ++cnt;
                }
            }
            if (__any(cnt > BUFN - 2)) flush();
#pragma unroll
            for (int s = 2; s < 4; ++s) {
                float dv = s == 2 ? d2 : d3;
                if (dv <= tau_f) {
                    unsigned u  = sortable_f32(dv);
                    unsigned lo = (u << 12) | (unsigned)(jg + jl + s);
                    unsigned hi = 0x43300000u | (u >> 20);
                    buf[cnt * 256 + tid] =
                        ((unsigned long long)hi << 32) | (unsigned long long)lo;
                    ++cnt;
                }
            }
            if (__any(cnt > BUFN - 2)) flush();
        }
    }

    // final drain (no tau needed)
    for (int k = 0; k < BUFN; ++k) {
        if (!__any(cnt > k)) break;
        unsigned long long kb = buf[k * 256 + tid];
        double key = (k < cnt) ? __longlong_as_double(kb)
                               : __longlong_as_double(SENT_BITS);
#pragma unroll
        for (int kk = KNN-1; kk > 0; --kk) {
            double mn = fmin(kd[kk], key);
            kd[kk] = fmax(kd[kk-1], mn);
        }
        kd[0] = fmin(kd[0], key);
    }

    // destructive 16-lane merge (r8 verbatim) -> res[] = original indices
    unsigned res[KNN];
#pragma unroll
    for (int r = 0; r < KNN; ++r) {
        double h = kd[0];
#pragma unroll
        for (int m = 1; m <= 8; m <<= 1)
            h = fmin(h, __shfl_xor(h, m, LPQ));
        long long hb = __double_as_longlong(h);
        res[r] = (unsigned)(hb & 0xFFF);
        bool own = (__double_as_longlong(kd[0]) == hb);
#pragma unroll
        for (int t = 0; t < KNN-1; ++t) kd[t] = own ? kd[t+1] : kd[t];
        kd[KNN-1] = own ? __longlong_as_double(SENT_BITS) : kd[KNN-1];
    }

    // ---------- fused MLP, lane-parallel, BIT-IDENTICAL to r8 ----------
    const float* vb = vel + (size_t)b * NPTS * 3;

    const float* w0 = W1 + (2*p)   * 66;
    const float* w1 = W1 + (2*p+1) * 66;
    float a0 = b1[2*p], a1 = b1[2*p+1];
#pragma unroll
    for (int k = 1; k < KNN; ++k) {       // ff 0..29: relative positions
        const float* pn = pb + 3*(int)res[k];
        float dx = pn[0] - xq, dy = pn[1] - yq, dz = pn[2] - zq;
        int ff = 3*(k-1);
        a0 = fmaf(dx, w0[ff+0], a0); a1 = fmaf(dx, w1[ff+0], a1);
        a0 = fmaf(dy, w0[ff+1], a0); a1 = fmaf(dy, w1[ff+1], a1);
        a0 = fmaf(dz, w0[ff+2], a0); a1 = fmaf(dz, w1[ff+2], a1);
    }
#pragma unroll
    for (int k = 0; k < KNN; ++k) {       // ff 30..62: velocities
        const float* vn = vb + 3*(int)res[k];
        int ff = 30 + 3*k;
        a0 = fmaf(vn[0], w0[ff+0], a0); a1 = fmaf(vn[0], w1[ff+0], a1);
        a0 = fmaf(vn[1], w0[ff+1], a0); a1 = fmaf(vn[1], w1[ff+1], a1);
        a0 = fmaf(vn[2], w0[ff+2], a0); a1 = fmaf(vn[2], w1[ff+2], a1);
    }
    float c0i = initc[b*3+0], c1i = initc[b*3+1], c2i = initc[b*3+2];
    a0 = fmaf(c0i, w0[63], a0); a1 = fmaf(c0i, w1[63], a1);
    a0 = fmaf(c1i, w0[64], a0); a1 = fmaf(c1i, w1[64], a1);
    a0 = fmaf(c2i, w0[65], a0); a1 = fmaf(c2i, w1[65], a1);

    float h2 = b2[p];
    const float* w2 = W2 + p * 32;
#pragma unroll
    for (int ii = 0; ii < 32; ++ii) {
        float h1v = __shfl((ii & 1) ? a1 : a0, ii >> 1, LPQ);
        h2 = fmaf(h1v, w2[ii], h2);
    }
    int o3 = p < 6 ? p : 0;
    float po = b3[o3];
    const float* w3 = W3 + o3 * 16;
#pragma unroll
    for (int ii = 0; ii < 16; ++ii) {
        float h2v = __shfl(h2, ii, LPQ);
        po = fmaf(h2v, w3[ii], po);
    }
    float resid = (p == 0) ? xq : (p == 1) ? yq : (p == 2) ? zq : 0.0f;
    po += resid;                           // residual on first 3 channels

    if (p < 6)
        out[((size_t)b * NPTS + (size_t)i) * 6 + p] = po;
}

extern "C" void kernel_launch(void* const* d_in, const int* in_sizes, int n_in,
                              void* d_out, int out_size, void* d_ws, size_t ws_size,
                              hipStream_t stream) {
    const float* pos   = (const float*)d_in[0];
    const float* vel   = (const float*)d_in[1];
    const float* initc = (const float*)d_in[2];
    const float* W1    = (const float*)d_in[3];
    const float* b1    = (const float*)d_in[4];
    const float* W2    = (const float*)d_in[5];
    const float* b2    = (const float*)d_in[6];
    const float* W3    = (const float*)d_in[7];
    const float* b3    = (const float*)d_in[8];
    float* out = (float*)d_out;

    fused_kernel<<<dim3(BATCH * (NPTS / QPB)), dim3(256), 0, stream>>>(
        pos, vel, initc, W1, b1, W2, b2, W3, b3, out);
}